// Round 17
// baseline (217.586 us; speedup 1.0000x reference)
//
#include <hip/hip_runtime.h>
#include <hip/hip_bf16.h>
#include <type_traits>

#define T_LEN 2048
#define HN 32
#define KVHN 8

typedef unsigned short u16;
typedef unsigned int u32;
typedef __attribute__((ext_vector_type(8))) short bf16x8;
typedef __attribute__((ext_vector_type(4))) float f32x4;
typedef __attribute__((ext_vector_type(16))) float f32x16;

__device__ __forceinline__ u16 f2b(float f) {
  __hip_bfloat16 h = __float2bfloat16(f);
  return __builtin_bit_cast(u16, h);
}
__device__ __forceinline__ float b2f(u16 u) {
  return __bfloat162float(__builtin_bit_cast(__hip_bfloat16, u));
}
// packed f32x2 -> bf16x2 in one HW op (T12 primitive; no builtin on gfx950)
__device__ __forceinline__ u32 pk2(float a, float b) {
  u32 r;
  asm("v_cvt_pk_bf16_f32 %0, %1, %2" : "=v"(r) : "v"(a), "v"(b));
  return r;
}
// raw v_exp_f32: exact exp2, no libm denormal fixup. Inputs here are in
// (-inf, +8]; FTZ on the huge-negative masked values is desired.
__device__ __forceinline__ float fexp2(float x) {
  float r;
  asm("v_exp_f32 %0, %1" : "=v"(r) : "v"(x));
  return r;
}

__device__ __forceinline__ void gload_lds16(const void* g, void* l) {
  __builtin_amdgcn_global_load_lds(
      (const __attribute__((address_space(1))) u32*)g,
      (__attribute__((address_space(3))) u32*)l, 16, 0, 0);
}

// ---------------- fp32 -> bf16 convert, all 5 tensors in one launch --------
// vec8 ranges: x 1048576 | Wq 524288 | Wk 131072 | Wv 131072 | Wo 524288
__global__ __launch_bounds__(256) void cvt_all(const float* __restrict__ x,
                                               const float* __restrict__ Wq,
                                               const float* __restrict__ Wk,
                                               const float* __restrict__ Wv,
                                               const float* __restrict__ Wo,
                                               u16* __restrict__ xb, u16* __restrict__ wqb,
                                               u16* __restrict__ wkb, u16* __restrict__ wvb,
                                               u16* __restrict__ wob) {
  int i = blockIdx.x * 256 + threadIdx.x;
  const float* src;
  u16* dst;
  int off;
  if (i < 1048576)      { src = x;  dst = xb;  off = i; }
  else if (i < 1572864) { src = Wq; dst = wqb; off = i - 1048576; }
  else if (i < 1703936) { src = Wk; dst = wkb; off = i - 1572864; }
  else if (i < 1835008) { src = Wv; dst = wvb; off = i - 1703936; }
  else                  { src = Wo; dst = wob; off = i - 1835008; }
  float4 a = ((const float4*)src)[off * 2];
  float4 b = ((const float4*)src)[off * 2 + 1];
  union { u16 s[8]; uint4 v; } r;
  r.s[0] = f2b(a.x); r.s[1] = f2b(a.y); r.s[2] = f2b(a.z); r.s[3] = f2b(a.w);
  r.s[4] = f2b(b.x); r.s[5] = f2b(b.y); r.s[6] = f2b(b.z); r.s[7] = f2b(b.w);
  ((uint4*)dst)[off] = r.v;
}

// ======== core32: BK=32 m97-structure (round-14 exact) — best for K/V proj ==
// MODE: 0 = bf16 out, 1 = f32 out, 2 = bf16 out + RoPE (cos/sin/mul fused)
template <int MODE>
__device__ __forceinline__ void gemm_bt_core32(const u16* __restrict__ A,
                                               const u16* __restrict__ Bt,
                                               void* __restrict__ Cv,
                                               const float* __restrict__ cosT,
                                               const float* __restrict__ sinT, float mul,
                                               int brow, int bcol, int N, int K,
                                               u16* As, u16* Bs) {
  int tid = threadIdx.x;
  int w = tid >> 6, l = tid & 63;
  int wr = w >> 1, wc = w & 1;
  int lr = tid >> 2, lc = (tid & 3) * 8;
  f32x4 acc[4][4] = {};
  for (int k0 = 0; k0 < K; k0 += 32) {
    __syncthreads();
#pragma unroll
    for (int i = 0; i < 2; ++i) {
      gload_lds16(A + (size_t)(brow + i * 64 + lr) * K + k0 + lc,
                  (char*)As + i * 4096 + w * 1024);
      gload_lds16(Bt + (size_t)(bcol + i * 64 + lr) * K + k0 + lc,
                  (char*)Bs + i * 4096 + w * 1024);
    }
    __syncthreads();
    bf16x8 af[4], bfr[4];
#pragma unroll
    for (int m = 0; m < 4; ++m)
      af[m] = *(const bf16x8*)((const char*)As + (wr * 64 + m * 16 + (l & 15)) * 64 + (l >> 4) * 16);
#pragma unroll
    for (int n = 0; n < 4; ++n)
      bfr[n] = *(const bf16x8*)((const char*)Bs + (wc * 64 + n * 16 + (l & 15)) * 64 + (l >> 4) * 16);
#pragma unroll
    for (int m = 0; m < 4; ++m)
#pragma unroll
      for (int n = 0; n < 4; ++n)
        acc[m][n] = __builtin_amdgcn_mfma_f32_16x16x32_bf16(af[m], bfr[n], acc[m][n], 0, 0, 0);
  }
  if constexpr (MODE == 2) {
    u16* C = (u16*)Cv;
#pragma unroll
    for (int m = 0; m < 4; ++m)
#pragma unroll
      for (int n = 0; n < 2; ++n)
#pragma unroll
        for (int r = 0; r < 4; ++r) {
          int row = brow + wr * 64 + m * 16 + (l >> 4) * 4 + r;
          int t = row & (T_LEN - 1);
          int dlo = n * 16 + (l & 15);
          float c = cosT[t * 64 + dlo];
          float s = sinT[t * 64 + dlo];
          float lo = acc[m][n][r], hh = acc[m][n + 2][r];
          size_t base = (size_t)row * N + bcol + wc * 64 + n * 16 + (l & 15);
          C[base]      = f2b((lo * c - hh * s) * mul);
          C[base + 32] = f2b((hh * c + lo * s) * mul);
        }
  } else {
#pragma unroll
    for (int m = 0; m < 4; ++m)
#pragma unroll
      for (int n = 0; n < 4; ++n)
#pragma unroll
        for (int r = 0; r < 4; ++r) {
          size_t row = brow + wr * 64 + m * 16 + (l >> 4) * 4 + r;
          size_t col = bcol + wc * 64 + n * 16 + (l & 15);
          if constexpr (MODE == 1)
            ((float*)Cv)[row * N + col] = acc[m][n][r];
          else
            ((u16*)Cv)[row * N + col] = f2b(acc[m][n][r]);
        }
  }
}

// ======== core64: BK=64 + XOR-swizzled LDS — best for 2048-wide projections =
template <int MODE>
__device__ __forceinline__ void gemm_bt_core64(const u16* __restrict__ A,
                                               const u16* __restrict__ Bt,
                                               void* __restrict__ Cv,
                                               const float* __restrict__ cosT,
                                               const float* __restrict__ sinT, float mul,
                                               int brow, int bcol, int N, int K,
                                               u16* As, u16* Bs) {
  int tid = threadIdx.x;
  int w = tid >> 6, l = tid & 63;
  int wr = w >> 1, wc = w & 1;
  int lr = tid >> 3;                         // 0..31: row within 32-row group
  int lcs = (((tid & 7) ^ (lr & 7)) * 8);    // swizzled source col (elems)
  f32x4 acc[4][4] = {};
  for (int k0 = 0; k0 < K; k0 += 64) {
    __syncthreads();
#pragma unroll
    for (int i = 0; i < 4; ++i) {
      gload_lds16(A + (size_t)(brow + i * 32 + lr) * K + k0 + lcs,
                  (char*)As + i * 4096 + w * 1024);
      gload_lds16(Bt + (size_t)(bcol + i * 32 + lr) * K + k0 + lcs,
                  (char*)Bs + i * 4096 + w * 1024);
    }
    __syncthreads();
#pragma unroll
    for (int kc = 0; kc < 2; ++kc) {
      bf16x8 af[4], bfr[4];
      int chunk = ((kc * 4 + (l >> 4)) ^ (l & 7)) * 16;  // swizzled byte col
#pragma unroll
      for (int m = 0; m < 4; ++m)
        af[m] = *(const bf16x8*)((const char*)As + (wr * 64 + m * 16 + (l & 15)) * 128 + chunk);
#pragma unroll
      for (int n = 0; n < 4; ++n)
        bfr[n] = *(const bf16x8*)((const char*)Bs + (wc * 64 + n * 16 + (l & 15)) * 128 + chunk);
#pragma unroll
      for (int m = 0; m < 4; ++m)
#pragma unroll
        for (int n = 0; n < 4; ++n)
          acc[m][n] = __builtin_amdgcn_mfma_f32_16x16x32_bf16(af[m], bfr[n], acc[m][n], 0, 0, 0);
    }
  }
  if constexpr (MODE == 2) {
    u16* C = (u16*)Cv;
#pragma unroll
    for (int m = 0; m < 4; ++m)
#pragma unroll
      for (int n = 0; n < 2; ++n)
#pragma unroll
        for (int r = 0; r < 4; ++r) {
          int row = brow + wr * 64 + m * 16 + (l >> 4) * 4 + r;
          int t = row & (T_LEN - 1);
          int dlo = n * 16 + (l & 15);
          float c = cosT[t * 64 + dlo];
          float s = sinT[t * 64 + dlo];
          float lo = acc[m][n][r], hh = acc[m][n + 2][r];
          size_t base = (size_t)row * N + bcol + wc * 64 + n * 16 + (l & 15);
          C[base]      = f2b((lo * c - hh * s) * mul);
          C[base + 32] = f2b((hh * c + lo * s) * mul);
        }
  } else if constexpr (MODE == 1) {
#pragma unroll
    for (int m = 0; m < 4; ++m)
#pragma unroll
      for (int n = 0; n < 4; ++n)
#pragma unroll
        for (int r = 0; r < 4; ++r) {
          size_t row = brow + wr * 64 + m * 16 + (l >> 4) * 4 + r;
          size_t col = bcol + wc * 64 + n * 16 + (l & 15);
          ((float*)Cv)[row * N + col] = acc[m][n][r];
        }
  } else {
    u16* C = (u16*)Cv;
#pragma unroll
    for (int m = 0; m < 4; ++m)
#pragma unroll
      for (int n = 0; n < 4; ++n)
#pragma unroll
        for (int r = 0; r < 4; ++r) {
          size_t row = brow + wr * 64 + m * 16 + (l >> 4) * 4 + r;
          size_t col = bcol + wc * 64 + n * 16 + (l & 15);
          C[row * N + col] = f2b(acc[m][n][r]);
        }
  }
}

template <int MODE>
__global__ __launch_bounds__(256) void gemm_bt(const u16* __restrict__ A,
                                               const u16* __restrict__ Bt,
                                               void* __restrict__ C,
                                               const float* __restrict__ cosT,
                                               const float* __restrict__ sinT,
                                               float mul, int N, int K) {
  __shared__ u16 As[128 * 64];
  __shared__ u16 Bs[128 * 64];
  gemm_bt_core64<MODE>(A, Bt, C, cosT, sinT, mul, blockIdx.y * 128, blockIdx.x * 128, N, K, As, Bs);
}

// K (rope) + V projections, BK=32 core (N=512 shape prefers it).
// grid = (8, 32): bx 0-3 -> K tile, 4-7 -> V tile.
__global__ __launch_bounds__(256) void gemm_kv(const u16* __restrict__ A,
                                               const u16* __restrict__ Wk,
                                               const u16* __restrict__ Wv,
                                               u16* __restrict__ Ko,
                                               u16* __restrict__ Vo,
                                               const float* __restrict__ cosT,
                                               const float* __restrict__ sinT) {
  __shared__ u16 As[128 * 32];
  __shared__ u16 Bs[128 * 32];
  int bx = blockIdx.x, brow = blockIdx.y * 128;
  if (bx < 4)
    gemm_bt_core32<2>(A, Wk, Ko, cosT, sinT, 1.0f, brow, bx * 128, 512, 2048, As, Bs);
  else
    gemm_bt_core32<0>(A, Wv, Vo, nullptr, nullptr, 0.f, brow, (bx - 4) * 128, 512, 2048, As, Bs);
}

// ---------------- causal flash attention, 32x32 swapped-QK^T ----------------
// Round-14 green kernel (78 us), byte-identical.
#define MKFRAG(SS, RB, OUTV)                                              \
  {                                                                       \
    u32 a_ = pk2(SS[RB + 0], SS[RB + 1]);                                 \
    u32 b_ = pk2(SS[RB + 4], SS[RB + 5]);                                 \
    u32 c_ = pk2(SS[RB + 2], SS[RB + 3]);                                 \
    u32 d_ = pk2(SS[RB + 6], SS[RB + 7]);                                 \
    asm volatile("v_permlane32_swap_b32 %0, %1" : "+v"(a_), "+v"(b_));    \
    asm volatile("v_permlane32_swap_b32 %0, %1" : "+v"(c_), "+v"(d_));    \
    union { u32 u[4]; bf16x8 v; } r_;                                     \
    r_.u[0] = a_; r_.u[1] = c_; r_.u[2] = b_; r_.u[3] = d_;               \
    OUTV = r_.v;                                                          \
  }

// S = QK^T + mask + online softmax (log2 domain) for one side.
#define SIDE_S(S0, S1, QF, Q0, MX, LS, O0, O1)                            \
  {                                                                       \
    S0 = (f32x16){}; S1 = (f32x16){};                                     \
    const char* kbuf = lds + cur * 8192;                                  \
    __builtin_amdgcn_s_setprio(1);                                        \
    _Pragma("unroll")                                                     \
    for (int ks = 0; ks < 4; ++ks) {                                      \
      int kbi = 2 * ks + hi;                                              \
      int R0 = lq, R1 = 32 + lq;                                          \
      bf16x8 k0 = *(const bf16x8*)(kbuf + R0 * 128 + ((kbi ^ (R0 & 7)) * 16)); \
      bf16x8 k1 = *(const bf16x8*)(kbuf + R1 * 128 + ((kbi ^ (R1 & 7)) * 16)); \
      S0 = __builtin_amdgcn_mfma_f32_32x32x16_bf16(k0, QF[ks], S0, 0, 0, 0); \
      S1 = __builtin_amdgcn_mfma_f32_32x32x16_bf16(k1, QF[ks], S1, 0, 0, 0); \
    }                                                                     \
    __builtin_amdgcn_s_setprio(0);                                        \
    if (kv0 + 63 > Q0) {                                                  \
      int qa = Q0 + lq;                                                   \
      _Pragma("unroll")                                                   \
      for (int r = 0; r < 16; ++r) {                                      \
        int kvl = (r & 3) + 8 * (r >> 2) + 4 * hi;                        \
        if (kv0 + kvl > qa) S0[r] = -1e30f;                               \
        if (kv0 + 32 + kvl > qa) S1[r] = -1e30f;                          \
      }                                                                   \
    }                                                                     \
    float a0 = fmaxf(S0[0], S1[0]);                                       \
    float a1 = fmaxf(S0[1], S1[1]);                                       \
    float a2 = fmaxf(S0[2], S1[2]);                                       \
    float a3 = fmaxf(S0[3], S1[3]);                                       \
    _Pragma("unroll")                                                     \
    for (int r = 4; r < 16; r += 4) {                                     \
      a0 = fmaxf(fmaxf(S0[r], S1[r]), a0);                                \
      a1 = fmaxf(fmaxf(S0[r + 1], S1[r + 1]), a1);                        \
      a2 = fmaxf(fmaxf(S0[r + 2], S1[r + 2]), a2);                        \
      a3 = fmaxf(fmaxf(S0[r + 3], S1[r + 3]), a3);                        \
    }                                                                     \
    float rm = fmaxf(fmaxf(a0, a1), fmaxf(a2, a3));                       \
    rm = fmaxf(rm, __shfl_xor(rm, 32));                                   \
    float nm = MX;                                                        \
    if (!__all(rm <= MX + 8.0f)) {                                        \
      nm = fmaxf(MX, rm);                                                 \
      float fac = fexp2(MX - nm);                                         \
      MX = nm;                                                            \
      LS *= fac;                                                          \
      _Pragma("unroll")                                                   \
      for (int r = 0; r < 16; ++r) { O0[r] *= fac; O1[r] *= fac; }        \
    }                                                                     \
    float p0 = 0.f, p1 = 0.f, p2 = 0.f, p3 = 0.f;                         \
    _Pragma("unroll")                                                     \
    for (int r = 0; r < 16; r += 4) {                                     \
      p0 += (S0[r]     = fexp2(S0[r]     - nm));                          \
      p1 += (S0[r + 1] = fexp2(S0[r + 1] - nm));                          \
      p2 += (S0[r + 2] = fexp2(S0[r + 2] - nm));                          \
      p3 += (S0[r + 3] = fexp2(S0[r + 3] - nm));                          \
    }                                                                     \
    _Pragma("unroll")                                                     \
    for (int r = 0; r < 16; r += 4) {                                     \
      p0 += (S1[r]     = fexp2(S1[r]     - nm));                          \
      p1 += (S1[r + 1] = fexp2(S1[r + 1] - nm));                          \
      p2 += (S1[r + 2] = fexp2(S1[r + 2] - nm));                          \
      p3 += (S1[r + 3] = fexp2(S1[r + 3] - nm));                          \
    }                                                                     \
    LS += (p0 + p1) + (p2 + p3);                                          \
  }

// P fragments + PV for one side (reads vt[cur]).
#define SIDE_PV(S0, S1, O0, O1)                                           \
  {                                                                       \
    const u32* vt = (const u32*)(lds + 16384 + cur * 8704);               \
    _Pragma("unroll")                                                     \
    for (int sl = 0; sl < 4; ++sl) {                                      \
      bf16x8 paf;                                                         \
      if (sl == 0)      MKFRAG(S0, 0, paf)                                \
      else if (sl == 1) MKFRAG(S0, 8, paf)                                \
      else if (sl == 2) MKFRAG(S1, 0, paf)                                \
      else              MKFRAG(S1, 8, paf)                                \
      int m0 = 8 * sl + 4 * hi;                                           \
      __builtin_amdgcn_s_setprio(1);                                      \
      _Pragma("unroll")                                                   \
      for (int g = 0; g < 2; ++g) {                                       \
        int d = lq + 32 * g;                                              \
        const u32* vp = vt + d * 34 + m0;                                 \
        union { u32 u[4]; bf16x8 v; } vv;                                 \
        uint2 lo = *(const uint2*)vp;                                     \
        uint2 hi2 = *(const uint2*)(vp + 2);                              \
        vv.u[0] = lo.x; vv.u[1] = lo.y; vv.u[2] = hi2.x; vv.u[3] = hi2.y; \
        if (g == 0) O0 = __builtin_amdgcn_mfma_f32_32x32x16_bf16(vv.v, paf, O0, 0, 0, 0); \
        else        O1 = __builtin_amdgcn_mfma_f32_32x32x16_bf16(vv.v, paf, O1, 0, 0, 0); \
      }                                                                   \
      __builtin_amdgcn_s_setprio(0);                                      \
    }                                                                     \
  }

// normalize + LDS-transpose + coalesced store for one side.
#define SIDE_STORE(O0, O1, LS, Q0)                                        \
  {                                                                       \
    float lsum = LS + __shfl_xor(LS, 32);                                 \
    float inv = 1.f / lsum;                                               \
    char* od = lds + w * 4096;                                            \
    _Pragma("unroll")                                                     \
    for (int g = 0; g < 2; ++g) {                                         \
      _Pragma("unroll")                                                   \
      for (int r = 0; r < 16; r += 2) {                                   \
        int d = (r & 3) + 8 * (r >> 2) + 4 * hi + 32 * g;                 \
        float e0 = (g ? O1[r] : O0[r]) * inv;                             \
        float e1 = (g ? O1[r + 1] : O0[r + 1]) * inv;                     \
        *(u32*)(od + lq * 128 + ((d * 2) ^ ((lq & 7) << 4))) = pk2(e0, e1); \
      }                                                                   \
    }                                                                     \
    __syncthreads();                                                      \
    _Pragma("unroll")                                                     \
    for (int i = 0; i < 4; ++i) {                                         \
      int q = l >> 1;                                                     \
      int c = (l & 1) * 4 + i;                                            \
      uint4 vv = *(const uint4*)(od + q * 128 + ((c * 16) ^ ((q & 7) << 4))); \
      *(uint4*)(O + ((bT + Q0 + q) * HN + h) * 64 + c * 8) = vv;          \
    }                                                                     \
  }

__global__ __launch_bounds__(256, 2) void attn_kernel(const u16* __restrict__ Q,
                                                      const u16* __restrict__ K,
                                                      const u16* __restrict__ V,
                                                      u16* __restrict__ O) {
  int qp = blockIdx.x, h = blockIdx.y, b = blockIdx.z;
  int kvh = h >> 2;
  const size_t bT = (size_t)b * T_LEN;
  __shared__ char lds[33792];

  int tid = threadIdx.x;
  int w = tid >> 6, l = tid & 63;
  int lq = l & 31;
  int hi = l >> 5;
  int qiL = qp, qiH = 15 - qp;
  int q0L = qiL * 128 + w * 32;
  int q0H = qiH * 128 + w * 32;
  int nt = 2 * qiH + 2;   // = 32 - 2*qp; covers both sides (L active first 2qp+2)

  // ---- stage Q for both sides (swizzled source), read frags ----
  bf16x8 qfL[4], qfH[4];
#pragma unroll
  for (int i = 0; i < 4; ++i) {
    int u = (i * 4 + w) * 64 + l;
    int row = u >> 3, blk = (u & 7) ^ (row & 7);
    gload_lds16(Q + ((bT + qiL * 128 + row) * HN + h) * 64 + blk * 8,
                lds + (i * 4 + w) * 1024);
  }
  __syncthreads();
  {
    int R = w * 32 + lq;
#pragma unroll
    for (int ks = 0; ks < 4; ++ks) {
      int kb = 2 * ks + hi;
      qfL[ks] = *(const bf16x8*)(lds + R * 128 + ((kb ^ (R & 7)) * 16));
    }
  }
  __syncthreads();
#pragma unroll
  for (int i = 0; i < 4; ++i) {
    int u = (i * 4 + w) * 64 + l;
    int row = u >> 3, blk = (u & 7) ^ (row & 7);
    gload_lds16(Q + ((bT + qiH * 128 + row) * HN + h) * 64 + blk * 8,
                lds + (i * 4 + w) * 1024);
  }
  __syncthreads();
  {
    int R = w * 32 + lq;
#pragma unroll
    for (int ks = 0; ks < 4; ++ks) {
      int kb = 2 * ks + hi;
      qfH[ks] = *(const bf16x8*)(lds + R * 128 + ((kb ^ (R & 7)) * 16));
    }
  }
  __syncthreads();

  // ---- V reg-stage state ----
  int r2 = tid >> 3;            // kv-pair 0..31
  int d0v = (tid & 7) * 8;      // d chunk
  uint4 va, vb;

  // ---- stage tile 0 ----
  {
#pragma unroll
    for (int i = 0; i < 2; ++i) {
      int u = (w * 2 + i) * 64 + l;
      int row = u >> 3, blk = (u & 7) ^ (row & 7);
      gload_lds16(K + ((bT + row) * KVHN + kvh) * 64 + blk * 8,
                  lds + (w * 2 + i) * 1024);
    }
    const u16* g0 = V + ((bT + 2 * r2) * KVHN + kvh) * 64 + d0v;
    va = *(const uint4*)g0;
    vb = *(const uint4*)(g0 + KVHN * 64);
    u32* vt = (u32*)(lds + 16384);
    const u16* pa = (const u16*)&va;
    const u16* pb = (const u16*)&vb;
#pragma unroll
    for (int j = 0; j < 8; ++j)
      vt[(d0v + j) * 34 + r2] = (u32)pa[j] | ((u32)pb[j] << 16);
  }

  f32x16 oL0 = {}, oL1 = {}, oH0 = {}, oH1 = {};
  float mxL = -1e30f, lsL = 0.f, mxH = -1e30f, lsH = 0.f;

  for (int t = 0; t < nt; ++t) {
    __syncthreads();   // staging of buf[t&1] complete; buf[t&1^1] free
    int cur = t & 1, nxt = cur ^ 1;
    bool last = (t + 1 >= nt);
    int kv0 = t * 64;
    bool actL = (kv0 <= q0L + 31);
    bool actH = (kv0 <= q0H + 31);

    // issue next-tile staging (overlaps with this tile's compute)
    if (!last) {
      int kvn = kv0 + 64;
#pragma unroll
      for (int i = 0; i < 2; ++i) {
        int u = (w * 2 + i) * 64 + l;
        int row = u >> 3, blk = (u & 7) ^ (row & 7);
        gload_lds16(K + ((bT + kvn + row) * KVHN + kvh) * 64 + blk * 8,
                    lds + nxt * 8192 + (w * 2 + i) * 1024);
      }
      const u16* g0 = V + ((bT + kvn + 2 * r2) * KVHN + kvh) * 64 + d0v;
      va = *(const uint4*)g0;
      vb = *(const uint4*)(g0 + KVHN * 64);
    }

    // independent register sets per side -> both chains can interleave
    f32x16 sL0, sL1, sH0, sH1;
    if (actL) SIDE_S(sL0, sL1, qfL, q0L, mxL, lsL, oL0, oL1)
    if (actH) SIDE_S(sH0, sH1, qfH, q0H, mxH, lsH, oH0, oH1)

    // write next-tile V (pair-packed transpose) into the other buffer
    if (!last) {
      u32* vt = (u32*)(lds + 16384 + nxt * 8704);
      const u16* pa = (const u16*)&va;
      const u16* pb = (const u16*)&vb;
#pragma unroll
      for (int j = 0; j < 8; ++j)
        vt[(d0v + j) * 34 + r2] = (u32)pa[j] | ((u32)pb[j] << 16);
    }

    if (actL) SIDE_PV(sL0, sL1, oL0, oL1)
    if (actH) SIDE_PV(sH0, sH1, oH0, oH1)
  }

  // ---- epilogues: L then H (od region reused; barriers between phases) ----
  __syncthreads();
  SIDE_STORE(oL0, oL1, lsL, q0L)
  __syncthreads();
  SIDE_STORE(oH0, oH1, lsH, q0H)
}

extern "C" void kernel_launch(void* const* d_in, const int* in_sizes, int n_in,
                              void* d_out, int out_size, void* d_ws, size_t ws_size,
                              hipStream_t stream) {
  const float* x    = (const float*)d_in[0];
  const float* Wq   = (const float*)d_in[1];
  const float* Wk   = (const float*)d_in[2];
  const float* Wv   = (const float*)d_in[3];
  const float* Wo   = (const float*)d_in[4];
  const float* cosT = (const float*)d_in[5];
  const float* sinT = (const float*)d_in[6];

  char* ws = (char*)d_ws;
  u16* xb  = (u16*)(ws + 0);          // 16 MB
  u16* wqb = (u16*)(ws + 16777216);   //  8 MB
  u16* wkb = (u16*)(ws + 25165824);   //  2 MB
  u16* wvb = (u16*)(ws + 27262976);   //  2 MB
  u16* wob = (u16*)(ws + 29360128);   //  8 MB
  u16* qb  = (u16*)(ws + 37748736);   // 16 MB
  u16* kb  = (u16*)(ws + 54525952);   //  4 MB
  u16* vb  = (u16*)(ws + 58720256);   //  4 MB
  u16* aob = (u16*)(ws + 62914560);   // 16 MB

  cvt_all<<<9216, 256, 0, stream>>>(x, Wq, Wk, Wv, Wo, xb, wqb, wkb, wvb, wob);

  // Q projection (rope + 1/8*log2e scale), core64 — same shape as O-proj
  gemm_bt<2><<<dim3(16, 32), 256, 0, stream>>>(xb, wqb, qb, cosT, sinT, 0.18033688f, 2048, 2048);
  // K (rope) + V projections, core32
  gemm_kv<<<dim3(8, 32), 256, 0, stream>>>(xb, wkb, wvb, kb, vb, cosT, sinT);

  attn_kernel<<<dim3(8, 32, 2), 256, 0, stream>>>(qb, kb, vb, aob);

  gemm_bt<1><<<dim3(16, 32), 256, 0, stream>>>(aob, wob, d_out, nullptr, nullptr, 0.f, 2048, 2048);
}

// Round 18
// 196.834 us; speedup vs baseline: 1.1054x; 1.1054x over previous
//
#include <hip/hip_runtime.h>
#include <hip/hip_bf16.h>
#include <type_traits>

#define T_LEN 2048
#define HN 32
#define KVHN 8

typedef unsigned short u16;
typedef unsigned int u32;
typedef __attribute__((ext_vector_type(8))) short bf16x8;
typedef __attribute__((ext_vector_type(4))) float f32x4;
typedef __attribute__((ext_vector_type(16))) float f32x16;

__device__ __forceinline__ u16 f2b(float f) {
  __hip_bfloat16 h = __float2bfloat16(f);
  return __builtin_bit_cast(u16, h);
}
__device__ __forceinline__ float b2f(u16 u) {
  return __bfloat162float(__builtin_bit_cast(__hip_bfloat16, u));
}
// packed f32x2 -> bf16x2 in one HW op (T12 primitive; no builtin on gfx950)
__device__ __forceinline__ u32 pk2(float a, float b) {
  u32 r;
  asm("v_cvt_pk_bf16_f32 %0, %1, %2" : "=v"(r) : "v"(a), "v"(b));
  return r;
}
// raw v_exp_f32: exact exp2, no libm denormal fixup. Inputs here are in
// (-inf, +8]; FTZ on the huge-negative masked values is desired.
__device__ __forceinline__ float fexp2(float x) {
  float r;
  asm("v_exp_f32 %0, %1" : "=v"(r) : "v"(x));
  return r;
}

__device__ __forceinline__ void gload_lds16(const void* g, void* l) {
  __builtin_amdgcn_global_load_lds(
      (const __attribute__((address_space(1))) u32*)g,
      (__attribute__((address_space(3))) u32*)l, 16, 0, 0);
}

// ---------------- fp32 -> bf16 convert, all 5 tensors in one launch --------
// vec8 ranges: x 1048576 | Wq 524288 | Wk 131072 | Wv 131072 | Wo 524288
__global__ __launch_bounds__(256) void cvt_all(const float* __restrict__ x,
                                               const float* __restrict__ Wq,
                                               const float* __restrict__ Wk,
                                               const float* __restrict__ Wv,
                                               const float* __restrict__ Wo,
                                               u16* __restrict__ xb, u16* __restrict__ wqb,
                                               u16* __restrict__ wkb, u16* __restrict__ wvb,
                                               u16* __restrict__ wob) {
  int i = blockIdx.x * 256 + threadIdx.x;
  const float* src;
  u16* dst;
  int off;
  if (i < 1048576)      { src = x;  dst = xb;  off = i; }
  else if (i < 1572864) { src = Wq; dst = wqb; off = i - 1048576; }
  else if (i < 1703936) { src = Wk; dst = wkb; off = i - 1572864; }
  else if (i < 1835008) { src = Wv; dst = wvb; off = i - 1703936; }
  else                  { src = Wo; dst = wob; off = i - 1835008; }
  float4 a = ((const float4*)src)[off * 2];
  float4 b = ((const float4*)src)[off * 2 + 1];
  union { u16 s[8]; uint4 v; } r;
  r.s[0] = f2b(a.x); r.s[1] = f2b(a.y); r.s[2] = f2b(a.z); r.s[3] = f2b(a.w);
  r.s[4] = f2b(b.x); r.s[5] = f2b(b.y); r.s[6] = f2b(b.z); r.s[7] = f2b(b.w);
  ((uint4*)dst)[off] = r.v;
}

// ======== core32: BK=32 m97-structure (round-14 exact) — best for gemm_qkv ==
// MODE: 0 = bf16 out, 1 = f32 out, 2 = bf16 out + RoPE (cos/sin/mul fused)
template <int MODE>
__device__ __forceinline__ void gemm_bt_core32(const u16* __restrict__ A,
                                               const u16* __restrict__ Bt,
                                               void* __restrict__ Cv,
                                               const float* __restrict__ cosT,
                                               const float* __restrict__ sinT, float mul,
                                               int brow, int bcol, int N, int K,
                                               u16* As, u16* Bs) {
  int tid = threadIdx.x;
  int w = tid >> 6, l = tid & 63;
  int wr = w >> 1, wc = w & 1;
  int lr = tid >> 2, lc = (tid & 3) * 8;
  f32x4 acc[4][4] = {};
  for (int k0 = 0; k0 < K; k0 += 32) {
    __syncthreads();
#pragma unroll
    for (int i = 0; i < 2; ++i) {
      gload_lds16(A + (size_t)(brow + i * 64 + lr) * K + k0 + lc,
                  (char*)As + i * 4096 + w * 1024);
      gload_lds16(Bt + (size_t)(bcol + i * 64 + lr) * K + k0 + lc,
                  (char*)Bs + i * 4096 + w * 1024);
    }
    __syncthreads();
    bf16x8 af[4], bfr[4];
#pragma unroll
    for (int m = 0; m < 4; ++m)
      af[m] = *(const bf16x8*)((const char*)As + (wr * 64 + m * 16 + (l & 15)) * 64 + (l >> 4) * 16);
#pragma unroll
    for (int n = 0; n < 4; ++n)
      bfr[n] = *(const bf16x8*)((const char*)Bs + (wc * 64 + n * 16 + (l & 15)) * 64 + (l >> 4) * 16);
#pragma unroll
    for (int m = 0; m < 4; ++m)
#pragma unroll
      for (int n = 0; n < 4; ++n)
        acc[m][n] = __builtin_amdgcn_mfma_f32_16x16x32_bf16(af[m], bfr[n], acc[m][n], 0, 0, 0);
  }
  if constexpr (MODE == 2) {
    u16* C = (u16*)Cv;
#pragma unroll
    for (int m = 0; m < 4; ++m)
#pragma unroll
      for (int n = 0; n < 2; ++n)
#pragma unroll
        for (int r = 0; r < 4; ++r) {
          int row = brow + wr * 64 + m * 16 + (l >> 4) * 4 + r;
          int t = row & (T_LEN - 1);
          int dlo = n * 16 + (l & 15);
          float c = cosT[t * 64 + dlo];
          float s = sinT[t * 64 + dlo];
          float lo = acc[m][n][r], hh = acc[m][n + 2][r];
          size_t base = (size_t)row * N + bcol + wc * 64 + n * 16 + (l & 15);
          C[base]      = f2b((lo * c - hh * s) * mul);
          C[base + 32] = f2b((hh * c + lo * s) * mul);
        }
  } else {
#pragma unroll
    for (int m = 0; m < 4; ++m)
#pragma unroll
      for (int n = 0; n < 4; ++n)
#pragma unroll
        for (int r = 0; r < 4; ++r) {
          size_t row = brow + wr * 64 + m * 16 + (l >> 4) * 4 + r;
          size_t col = bcol + wc * 64 + n * 16 + (l & 15);
          if constexpr (MODE == 1)
            ((float*)Cv)[row * N + col] = acc[m][n][r];
          else
            ((u16*)Cv)[row * N + col] = f2b(acc[m][n][r]);
        }
  }
}

// ======== core64: BK=64 + XOR-swizzled LDS (round-15 exact) — best for O-proj
template <int MODE>
__device__ __forceinline__ void gemm_bt_core64(const u16* __restrict__ A,
                                               const u16* __restrict__ Bt,
                                               void* __restrict__ Cv,
                                               const float* __restrict__ cosT,
                                               const float* __restrict__ sinT, float mul,
                                               int brow, int bcol, int N, int K,
                                               u16* As, u16* Bs) {
  int tid = threadIdx.x;
  int w = tid >> 6, l = tid & 63;
  int wr = w >> 1, wc = w & 1;
  int lr = tid >> 3;                         // 0..31: row within 32-row group
  int lcs = (((tid & 7) ^ (lr & 7)) * 8);    // swizzled source col (elems)
  f32x4 acc[4][4] = {};
  for (int k0 = 0; k0 < K; k0 += 64) {
    __syncthreads();
#pragma unroll
    for (int i = 0; i < 4; ++i) {
      gload_lds16(A + (size_t)(brow + i * 32 + lr) * K + k0 + lcs,
                  (char*)As + i * 4096 + w * 1024);
      gload_lds16(Bt + (size_t)(bcol + i * 32 + lr) * K + k0 + lcs,
                  (char*)Bs + i * 4096 + w * 1024);
    }
    __syncthreads();
#pragma unroll
    for (int kc = 0; kc < 2; ++kc) {
      bf16x8 af[4], bfr[4];
      int chunk = ((kc * 4 + (l >> 4)) ^ (l & 7)) * 16;  // swizzled byte col
#pragma unroll
      for (int m = 0; m < 4; ++m)
        af[m] = *(const bf16x8*)((const char*)As + (wr * 64 + m * 16 + (l & 15)) * 128 + chunk);
#pragma unroll
      for (int n = 0; n < 4; ++n)
        bfr[n] = *(const bf16x8*)((const char*)Bs + (wc * 64 + n * 16 + (l & 15)) * 128 + chunk);
#pragma unroll
      for (int m = 0; m < 4; ++m)
#pragma unroll
        for (int n = 0; n < 4; ++n)
          acc[m][n] = __builtin_amdgcn_mfma_f32_16x16x32_bf16(af[m], bfr[n], acc[m][n], 0, 0, 0);
    }
  }
  if constexpr (MODE == 1) {
#pragma unroll
    for (int m = 0; m < 4; ++m)
#pragma unroll
      for (int n = 0; n < 4; ++n)
#pragma unroll
        for (int r = 0; r < 4; ++r) {
          size_t row = brow + wr * 64 + m * 16 + (l >> 4) * 4 + r;
          size_t col = bcol + wc * 64 + n * 16 + (l & 15);
          ((float*)Cv)[row * N + col] = acc[m][n][r];
        }
  } else {
    u16* C = (u16*)Cv;
#pragma unroll
    for (int m = 0; m < 4; ++m)
#pragma unroll
      for (int n = 0; n < 4; ++n)
#pragma unroll
        for (int r = 0; r < 4; ++r) {
          size_t row = brow + wr * 64 + m * 16 + (l >> 4) * 4 + r;
          size_t col = bcol + wc * 64 + n * 16 + (l & 15);
          C[row * N + col] = f2b(acc[m][n][r]);
        }
  }
}

template <int MODE>
__global__ __launch_bounds__(256) void gemm_bt(const u16* __restrict__ A,
                                               const u16* __restrict__ Bt,
                                               void* __restrict__ C,
                                               const float* __restrict__ cosT,
                                               const float* __restrict__ sinT,
                                               float mul, int N, int K) {
  __shared__ u16 As[128 * 64];
  __shared__ u16 Bs[128 * 64];
  gemm_bt_core64<MODE>(A, Bt, C, cosT, sinT, mul, blockIdx.y * 128, blockIdx.x * 128, N, K, As, Bs);
}

// fused Q (rope + scale; 1/8 * log2e so attention S arrives in log2 domain),
// K (rope), V projections in one launch — BK=32 core (empirically faster here).
// grid = (24, 32): bx 0-15 -> Q tile, 16-19 -> K tile, 20-23 -> V tile.
__global__ __launch_bounds__(256) void gemm_qkv(const u16* __restrict__ A,
                                                const u16* __restrict__ Wq,
                                                const u16* __restrict__ Wk,
                                                const u16* __restrict__ Wv,
                                                u16* __restrict__ Qo,
                                                u16* __restrict__ Ko,
                                                u16* __restrict__ Vo,
                                                const float* __restrict__ cosT,
                                                const float* __restrict__ sinT) {
  __shared__ u16 As[128 * 32];
  __shared__ u16 Bs[128 * 32];
  int bx = blockIdx.x, brow = blockIdx.y * 128;
  if (bx < 16)
    gemm_bt_core32<2>(A, Wq, Qo, cosT, sinT, 0.18033688f, brow, bx * 128, 2048, 2048, As, Bs);
  else if (bx < 20)
    gemm_bt_core32<2>(A, Wk, Ko, cosT, sinT, 1.0f, brow, (bx - 16) * 128, 512, 2048, As, Bs);
  else
    gemm_bt_core32<0>(A, Wv, Vo, nullptr, nullptr, 0.f, brow, (bx - 20) * 128, 512, 2048, As, Bs);
}

// ---------------- causal flash attention, 32x32 swapped-QK^T ----------------
// Round-14 green kernel (78 us), byte-identical.
#define MKFRAG(SS, RB, OUTV)                                              \
  {                                                                       \
    u32 a_ = pk2(SS[RB + 0], SS[RB + 1]);                                 \
    u32 b_ = pk2(SS[RB + 4], SS[RB + 5]);                                 \
    u32 c_ = pk2(SS[RB + 2], SS[RB + 3]);                                 \
    u32 d_ = pk2(SS[RB + 6], SS[RB + 7]);                                 \
    asm volatile("v_permlane32_swap_b32 %0, %1" : "+v"(a_), "+v"(b_));    \
    asm volatile("v_permlane32_swap_b32 %0, %1" : "+v"(c_), "+v"(d_));    \
    union { u32 u[4]; bf16x8 v; } r_;                                     \
    r_.u[0] = a_; r_.u[1] = c_; r_.u[2] = b_; r_.u[3] = d_;               \
    OUTV = r_.v;                                                          \
  }

// S = QK^T + mask + online softmax (log2 domain) for one side.
#define SIDE_S(S0, S1, QF, Q0, MX, LS, O0, O1)                            \
  {                                                                       \
    S0 = (f32x16){}; S1 = (f32x16){};                                     \
    const char* kbuf = lds + cur * 8192;                                  \
    __builtin_amdgcn_s_setprio(1);                                        \
    _Pragma("unroll")                                                     \
    for (int ks = 0; ks < 4; ++ks) {                                      \
      int kbi = 2 * ks + hi;                                              \
      int R0 = lq, R1 = 32 + lq;                                          \
      bf16x8 k0 = *(const bf16x8*)(kbuf + R0 * 128 + ((kbi ^ (R0 & 7)) * 16)); \
      bf16x8 k1 = *(const bf16x8*)(kbuf + R1 * 128 + ((kbi ^ (R1 & 7)) * 16)); \
      S0 = __builtin_amdgcn_mfma_f32_32x32x16_bf16(k0, QF[ks], S0, 0, 0, 0); \
      S1 = __builtin_amdgcn_mfma_f32_32x32x16_bf16(k1, QF[ks], S1, 0, 0, 0); \
    }                                                                     \
    __builtin_amdgcn_s_setprio(0);                                        \
    if (kv0 + 63 > Q0) {                                                  \
      int qa = Q0 + lq;                                                   \
      _Pragma("unroll")                                                   \
      for (int r = 0; r < 16; ++r) {                                      \
        int kvl = (r & 3) + 8 * (r >> 2) + 4 * hi;                        \
        if (kv0 + kvl > qa) S0[r] = -1e30f;                               \
        if (kv0 + 32 + kvl > qa) S1[r] = -1e30f;                          \
      }                                                                   \
    }                                                                     \
    float a0 = fmaxf(S0[0], S1[0]);                                       \
    float a1 = fmaxf(S0[1], S1[1]);                                       \
    float a2 = fmaxf(S0[2], S1[2]);                                       \
    float a3 = fmaxf(S0[3], S1[3]);                                       \
    _Pragma("unroll")                                                     \
    for (int r = 4; r < 16; r += 4) {                                     \
      a0 = fmaxf(fmaxf(S0[r], S1[r]), a0);                                \
      a1 = fmaxf(fmaxf(S0[r + 1], S1[r + 1]), a1);                        \
      a2 = fmaxf(fmaxf(S0[r + 2], S1[r + 2]), a2);                        \
      a3 = fmaxf(fmaxf(S0[r + 3], S1[r + 3]), a3);                        \
    }                                                                     \
    float rm = fmaxf(fmaxf(a0, a1), fmaxf(a2, a3));                       \
    rm = fmaxf(rm, __shfl_xor(rm, 32));                                   \
    float nm = MX;                                                        \
    if (!__all(rm <= MX + 8.0f)) {                                        \
      nm = fmaxf(MX, rm);                                                 \
      float fac = fexp2(MX - nm);                                         \
      MX = nm;                                                            \
      LS *= fac;                                                          \
      _Pragma("unroll")                                                   \
      for (int r = 0; r < 16; ++r) { O0[r] *= fac; O1[r] *= fac; }        \
    }                                                                     \
    float p0 = 0.f, p1 = 0.f, p2 = 0.f, p3 = 0.f;                         \
    _Pragma("unroll")                                                     \
    for (int r = 0; r < 16; r += 4) {                                     \
      p0 += (S0[r]     = fexp2(S0[r]     - nm));                          \
      p1 += (S0[r + 1] = fexp2(S0[r + 1] - nm));                          \
      p2 += (S0[r + 2] = fexp2(S0[r + 2] - nm));                          \
      p3 += (S0[r + 3] = fexp2(S0[r + 3] - nm));                          \
    }                                                                     \
    _Pragma("unroll")                                                     \
    for (int r = 0; r < 16; r += 4) {                                     \
      p0 += (S1[r]     = fexp2(S1[r]     - nm));                          \
      p1 += (S1[r + 1] = fexp2(S1[r + 1] - nm));                          \
      p2 += (S1[r + 2] = fexp2(S1[r + 2] - nm));                          \
      p3 += (S1[r + 3] = fexp2(S1[r + 3] - nm));                          \
    }                                                                     \
    LS += (p0 + p1) + (p2 + p3);                                          \
  }

// P fragments + PV for one side (reads vt[cur]).
#define SIDE_PV(S0, S1, O0, O1)                                           \
  {                                                                       \
    const u32* vt = (const u32*)(lds + 16384 + cur * 8704);               \
    _Pragma("unroll")                                                     \
    for (int sl = 0; sl < 4; ++sl) {                                      \
      bf16x8 paf;                                                         \
      if (sl == 0)      MKFRAG(S0, 0, paf)                                \
      else if (sl == 1) MKFRAG(S0, 8, paf)                                \
      else if (sl == 2) MKFRAG(S1, 0, paf)                                \
      else              MKFRAG(S1, 8, paf)                                \
      int m0 = 8 * sl + 4 * hi;                                           \
      __builtin_amdgcn_s_setprio(1);                                      \
      _Pragma("unroll")                                                   \
      for (int g = 0; g < 2; ++g) {                                       \
        int d = lq + 32 * g;                                              \
        const u32* vp = vt + d * 34 + m0;                                 \
        union { u32 u[4]; bf16x8 v; } vv;                                 \
        uint2 lo = *(const uint2*)vp;                                     \
        uint2 hi2 = *(const uint2*)(vp + 2);                              \
        vv.u[0] = lo.x; vv.u[1] = lo.y; vv.u[2] = hi2.x; vv.u[3] = hi2.y; \
        if (g == 0) O0 = __builtin_amdgcn_mfma_f32_32x32x16_bf16(vv.v, paf, O0, 0, 0, 0); \
        else        O1 = __builtin_amdgcn_mfma_f32_32x32x16_bf16(vv.v, paf, O1, 0, 0, 0); \
      }                                                                   \
      __builtin_amdgcn_s_setprio(0);                                      \
    }                                                                     \
  }

// normalize + LDS-transpose + coalesced store for one side.
#define SIDE_STORE(O0, O1, LS, Q0)                                        \
  {                                                                       \
    float lsum = LS + __shfl_xor(LS, 32);                                 \
    float inv = 1.f / lsum;                                               \
    char* od = lds + w * 4096;                                            \
    _Pragma("unroll")                                                     \
    for (int g = 0; g < 2; ++g) {                                         \
      _Pragma("unroll")                                                   \
      for (int r = 0; r < 16; r += 2) {                                   \
        int d = (r & 3) + 8 * (r >> 2) + 4 * hi + 32 * g;                 \
        float e0 = (g ? O1[r] : O0[r]) * inv;                             \
        float e1 = (g ? O1[r + 1] : O0[r + 1]) * inv;                     \
        *(u32*)(od + lq * 128 + ((d * 2) ^ ((lq & 7) << 4))) = pk2(e0, e1); \
      }                                                                   \
    }                                                                     \
    __syncthreads();                                                      \
    _Pragma("unroll")                                                     \
    for (int i = 0; i < 4; ++i) {                                         \
      int q = l >> 1;                                                     \
      int c = (l & 1) * 4 + i;                                            \
      uint4 vv = *(const uint4*)(od + q * 128 + ((c * 16) ^ ((q & 7) << 4))); \
      *(uint4*)(O + ((bT + Q0 + q) * HN + h) * 64 + c * 8) = vv;          \
    }                                                                     \
  }

__global__ __launch_bounds__(256, 2) void attn_kernel(const u16* __restrict__ Q,
                                                      const u16* __restrict__ K,
                                                      const u16* __restrict__ V,
                                                      u16* __restrict__ O) {
  int qp = blockIdx.x, h = blockIdx.y, b = blockIdx.z;
  int kvh = h >> 2;
  const size_t bT = (size_t)b * T_LEN;
  __shared__ char lds[33792];

  int tid = threadIdx.x;
  int w = tid >> 6, l = tid & 63;
  int lq = l & 31;
  int hi = l >> 5;
  int qiL = qp, qiH = 15 - qp;
  int q0L = qiL * 128 + w * 32;
  int q0H = qiH * 128 + w * 32;
  int nt = 2 * qiH + 2;   // = 32 - 2*qp; covers both sides (L active first 2qp+2)

  // ---- stage Q for both sides (swizzled source), read frags ----
  bf16x8 qfL[4], qfH[4];
#pragma unroll
  for (int i = 0; i < 4; ++i) {
    int u = (i * 4 + w) * 64 + l;
    int row = u >> 3, blk = (u & 7) ^ (row & 7);
    gload_lds16(Q + ((bT + qiL * 128 + row) * HN + h) * 64 + blk * 8,
                lds + (i * 4 + w) * 1024);
  }
  __syncthreads();
  {
    int R = w * 32 + lq;
#pragma unroll
    for (int ks = 0; ks < 4; ++ks) {
      int kb = 2 * ks + hi;
      qfL[ks] = *(const bf16x8*)(lds + R * 128 + ((kb ^ (R & 7)) * 16));
    }
  }
  __syncthreads();
#pragma unroll
  for (int i = 0; i < 4; ++i) {
    int u = (i * 4 + w) * 64 + l;
    int row = u >> 3, blk = (u & 7) ^ (row & 7);
    gload_lds16(Q + ((bT + qiH * 128 + row) * HN + h) * 64 + blk * 8,
                lds + (i * 4 + w) * 1024);
  }
  __syncthreads();
  {
    int R = w * 32 + lq;
#pragma unroll
    for (int ks = 0; ks < 4; ++ks) {
      int kb = 2 * ks + hi;
      qfH[ks] = *(const bf16x8*)(lds + R * 128 + ((kb ^ (R & 7)) * 16));
    }
  }
  __syncthreads();

  // ---- V reg-stage state ----
  int r2 = tid >> 3;            // kv-pair 0..31
  int d0v = (tid & 7) * 8;      // d chunk
  uint4 va, vb;

  // ---- stage tile 0 ----
  {
#pragma unroll
    for (int i = 0; i < 2; ++i) {
      int u = (w * 2 + i) * 64 + l;
      int row = u >> 3, blk = (u & 7) ^ (row & 7);
      gload_lds16(K + ((bT + row) * KVHN + kvh) * 64 + blk * 8,
                  lds + (w * 2 + i) * 1024);
    }
    const u16* g0 = V + ((bT + 2 * r2) * KVHN + kvh) * 64 + d0v;
    va = *(const uint4*)g0;
    vb = *(const uint4*)(g0 + KVHN * 64);
    u32* vt = (u32*)(lds + 16384);
    const u16* pa = (const u16*)&va;
    const u16* pb = (const u16*)&vb;
#pragma unroll
    for (int j = 0; j < 8; ++j)
      vt[(d0v + j) * 34 + r2] = (u32)pa[j] | ((u32)pb[j] << 16);
  }

  f32x16 oL0 = {}, oL1 = {}, oH0 = {}, oH1 = {};
  float mxL = -1e30f, lsL = 0.f, mxH = -1e30f, lsH = 0.f;

  for (int t = 0; t < nt; ++t) {
    __syncthreads();   // staging of buf[t&1] complete; buf[t&1^1] free
    int cur = t & 1, nxt = cur ^ 1;
    bool last = (t + 1 >= nt);
    int kv0 = t * 64;
    bool actL = (kv0 <= q0L + 31);
    bool actH = (kv0 <= q0H + 31);

    // issue next-tile staging (overlaps with this tile's compute)
    if (!last) {
      int kvn = kv0 + 64;
#pragma unroll
      for (int i = 0; i < 2; ++i) {
        int u = (w * 2 + i) * 64 + l;
        int row = u >> 3, blk = (u & 7) ^ (row & 7);
        gload_lds16(K + ((bT + kvn + row) * KVHN + kvh) * 64 + blk * 8,
                    lds + nxt * 8192 + (w * 2 + i) * 1024);
      }
      const u16* g0 = V + ((bT + kvn + 2 * r2) * KVHN + kvh) * 64 + d0v;
      va = *(const uint4*)g0;
      vb = *(const uint4*)(g0 + KVHN * 64);
    }

    // independent register sets per side -> both chains can interleave
    f32x16 sL0, sL1, sH0, sH1;
    if (actL) SIDE_S(sL0, sL1, qfL, q0L, mxL, lsL, oL0, oL1)
    if (actH) SIDE_S(sH0, sH1, qfH, q0H, mxH, lsH, oH0, oH1)

    // write next-tile V (pair-packed transpose) into the other buffer
    if (!last) {
      u32* vt = (u32*)(lds + 16384 + nxt * 8704);
      const u16* pa = (const u16*)&va;
      const u16* pb = (const u16*)&vb;
#pragma unroll
      for (int j = 0; j < 8; ++j)
        vt[(d0v + j) * 34 + r2] = (u32)pa[j] | ((u32)pb[j] << 16);
    }

    if (actL) SIDE_PV(sL0, sL1, oL0, oL1)
    if (actH) SIDE_PV(sH0, sH1, oH0, oH1)
  }

  // ---- epilogues: L then H (od region reused; barriers between phases) ----
  __syncthreads();
  SIDE_STORE(oL0, oL1, lsL, q0L)
  __syncthreads();
  SIDE_STORE(oH0, oH1, lsH, q0H)
}

extern "C" void kernel_launch(void* const* d_in, const int* in_sizes, int n_in,
                              void* d_out, int out_size, void* d_ws, size_t ws_size,
                              hipStream_t stream) {
  const float* x    = (const float*)d_in[0];
  const float* Wq   = (const float*)d_in[1];
  const float* Wk   = (const float*)d_in[2];
  const float* Wv   = (const float*)d_in[3];
  const float* Wo   = (const float*)d_in[4];
  const float* cosT = (const float*)d_in[5];
  const float* sinT = (const float*)d_in[6];

  char* ws = (char*)d_ws;
  u16* xb  = (u16*)(ws + 0);          // 16 MB
  u16* wqb = (u16*)(ws + 16777216);   //  8 MB
  u16* wkb = (u16*)(ws + 25165824);   //  2 MB
  u16* wvb = (u16*)(ws + 27262976);   //  2 MB
  u16* wob = (u16*)(ws + 29360128);   //  8 MB
  u16* qb  = (u16*)(ws + 37748736);   // 16 MB
  u16* kb  = (u16*)(ws + 54525952);   //  4 MB
  u16* vb  = (u16*)(ws + 58720256);   //  4 MB
  u16* aob = (u16*)(ws + 62914560);   // 16 MB

  cvt_all<<<9216, 256, 0, stream>>>(x, Wq, Wk, Wv, Wo, xb, wqb, wkb, wvb, wob);

  gemm_qkv<<<dim3(24, 32), 256, 0, stream>>>(xb, wqb, wkb, wvb, qb, kb, vb, cosT, sinT);

  attn_kernel<<<dim3(8, 32, 2), 256, 0, stream>>>(qb, kb, vb, aob);

  gemm_bt<1><<<dim3(16, 32), 256, 0, stream>>>(aob, wob, d_out, nullptr, nullptr, 0.f, 2048, 2048);
}